// Round 1
// baseline (621.608 us; speedup 1.0000x reference)
//
#include <hip/hip_runtime.h>
#include <hip/hip_bf16.h>
#include <math.h>

#define NLAYER 4
#define BSZ 2
#define NHEADS 16
#define ILEN 1024
#define ELEN 588
#define HID 256
#define NROWS (BSZ * ILEN)        // 2048
#define NCH (NLAYER * NHEADS)     // 64
#define S_H ((size_t)(ILEN) * ELEN)          // 602112  (head stride)
#define S_B ((size_t)NHEADS * S_H)           // 9633792 (batch stride)
#define S_L ((size_t)BSZ * S_B)              // 19267584 (layer stride)

__device__ __forceinline__ float gelu_exact(float x) {
    return 0.5f * x * (1.0f + erff(x * 0.70710678118654752440f));
}
__device__ __forceinline__ float sigmoidf(float x) {
    return 1.0f / (1.0f + expf(-x));
}
__device__ __forceinline__ float wave_sum(float v) {
    #pragma unroll
    for (int m = 1; m < 64; m <<= 1) v += __shfl_xor(v, m);
    return v;
}

// ---------------------------------------------------------------------------
// Kernel A: heatmap channel-reduction + logits + LN0, one block per row.
// ---------------------------------------------------------------------------
__global__ __launch_bounds__(256) void k_reduce_ln0(
    const float* __restrict__ hm, const float* __restrict__ Wh,
    const float* __restrict__ bh, const float* __restrict__ Wk,
    const float* __restrict__ bk, const float* __restrict__ g0,
    const float* __restrict__ be0, float* __restrict__ y,
    float* __restrict__ keepf, float* __restrict__ out_logits)
{
    const int row = blockIdx.x;           // b*1024 + i
    const int b = row >> 10;
    const int i = row & 1023;
    const int tid = threadIdx.x;

    __shared__ float s_wh[NCH];
    __shared__ float s_wk[ELEN];
    __shared__ float s_red[12];
    __shared__ float s_bcast[2];

    if (tid < NCH) s_wh[tid] = Wh[tid];
    for (int e = tid; e < ELEN; e += 256) s_wk[e] = Wk[e];
    __syncthreads();

    const int f4 = tid;                   // active for f4 < 147 (147*4 = 588)
    float4 acc = make_float4(0.f, 0.f, 0.f, 0.f);

    if (f4 < 147) {
        const float* rowbase = hm + (size_t)b * S_B + (size_t)i * ELEN + (size_t)(f4 * 4);
        #pragma unroll 8
        for (int ch = 0; ch < NCH; ++ch) {
            const size_t off = (size_t)(ch >> 4) * S_L + (size_t)(ch & 15) * S_H;
            const float4 v = *(const float4*)(rowbase + off);
            const float w = s_wh[ch];
            acc.x += v.x * w; acc.y += v.y * w;
            acc.z += v.z * w; acc.w += v.w * w;
        }
        const float bhv = bh[0];
        acc.x += bhv; acc.y += bhv; acc.z += bhv; acc.w += bhv;
    }

    float sx = 0.f, sxx = 0.f, sk = 0.f;
    if (f4 < 147) {
        sx  = acc.x + acc.y + acc.z + acc.w;
        sxx = acc.x * acc.x + acc.y * acc.y + acc.z * acc.z + acc.w * acc.w;
        const float4 wk = *(const float4*)&s_wk[f4 * 4];
        sk  = acc.x * wk.x + acc.y * wk.y + acc.z * wk.z + acc.w * wk.w;
    }
    #pragma unroll
    for (int off = 32; off; off >>= 1) {
        sx  += __shfl_down(sx, off);
        sxx += __shfl_down(sxx, off);
        sk  += __shfl_down(sk, off);
    }
    const int wid = tid >> 6, lane = tid & 63;
    if (lane == 0) { s_red[wid] = sx; s_red[4 + wid] = sxx; s_red[8 + wid] = sk; }
    __syncthreads();
    if (tid == 0) {
        sx  = s_red[0] + s_red[1] + s_red[2] + s_red[3];
        sxx = s_red[4] + s_red[5] + s_red[6] + s_red[7];
        sk  = s_red[8] + s_red[9] + s_red[10] + s_red[11];
        const float mu   = sx * (1.0f / ELEN);
        const float var  = sxx * (1.0f / ELEN) - mu * mu;
        const float rstd = rsqrtf(var + 1e-5f);
        const float logit = sk + bk[0];
        s_bcast[0] = mu; s_bcast[1] = rstd;
        out_logits[row] = logit;
        keepf[row] = (logit > 0.f) ? 1.f : 0.f;
    }
    __syncthreads();
    if (f4 < 147) {
        const float mu = s_bcast[0], rstd = s_bcast[1];
        const float4 gv = *(const float4*)&g0[f4 * 4];
        const float4 bv = *(const float4*)&be0[f4 * 4];
        float4 o;
        o.x = (acc.x - mu) * rstd * gv.x + bv.x;
        o.y = (acc.y - mu) * rstd * gv.y + bv.y;
        o.z = (acc.z - mu) * rstd * gv.z + bv.z;
        o.w = (acc.w - mu) * rstd * gv.w + bv.w;
        *(float4*)&y[(size_t)row * ELEN + f4 * 4] = o;
    }
}

// ---------------------------------------------------------------------------
// Kernel C: GEMM0 (2048x588 @ 588x256) both branches + bias + GELU + LN1.
// 8 rows per block; 4 waves, each wave = 2 rows; 64 lanes x 4 cols = 256 cols.
// ---------------------------------------------------------------------------
__global__ __launch_bounds__(256) void k_mlp0(
    const float* __restrict__ y,
    const float* __restrict__ W10, const float* __restrict__ b10,
    const float* __restrict__ W20, const float* __restrict__ b20,
    const float* __restrict__ g1, const float* __restrict__ be1,
    float* __restrict__ h1n, float* __restrict__ h2n)
{
    __shared__ float y_lds[8][ELEN];
    const int tid  = threadIdx.x;
    const int row0 = blockIdx.x * 8;

    for (int fi = tid; fi < 8 * 147; fi += 256) {
        const int r = fi / 147, t = fi % 147;
        *(float4*)&y_lds[r][t * 4] =
            *(const float4*)&y[(size_t)(row0 + r) * ELEN + t * 4];
    }
    __syncthreads();

    const int lane = tid & 63;
    const int rg   = tid >> 6;
    const int col  = lane * 4;
    const int lr0  = rg * 2, lr1 = lr0 + 1;

    const float4 gg  = *(const float4*)&g1[col];
    const float4 bb1 = *(const float4*)&be1[col];

    #pragma unroll
    for (int br = 0; br < 2; ++br) {
        const float* W  = br ? W20 : W10;
        const float* bb = br ? b20 : b10;
        float4 a0 = make_float4(0.f, 0.f, 0.f, 0.f);
        float4 a1 = make_float4(0.f, 0.f, 0.f, 0.f);

        for (int e = 0; e < ELEN; e += 2) {
            const float2 ya = *(const float2*)&y_lds[lr0][e];
            const float2 yb = *(const float2*)&y_lds[lr1][e];
            const float4 w0 = *(const float4*)&W[(size_t)e * HID + col];
            const float4 w1 = *(const float4*)&W[(size_t)(e + 1) * HID + col];
            a0.x += ya.x * w0.x + ya.y * w1.x;
            a0.y += ya.x * w0.y + ya.y * w1.y;
            a0.z += ya.x * w0.z + ya.y * w1.z;
            a0.w += ya.x * w0.w + ya.y * w1.w;
            a1.x += yb.x * w0.x + yb.y * w1.x;
            a1.y += yb.x * w0.y + yb.y * w1.y;
            a1.z += yb.x * w0.z + yb.y * w1.z;
            a1.w += yb.x * w0.w + yb.y * w1.w;
        }

        const float4 bv = *(const float4*)&bb[col];
        float* hdst = br ? h2n : h1n;

        #pragma unroll
        for (int r = 0; r < 2; ++r) {
            float4 v = r ? a1 : a0;
            v.x = gelu_exact(v.x + bv.x);
            v.y = gelu_exact(v.y + bv.y);
            v.z = gelu_exact(v.z + bv.z);
            v.w = gelu_exact(v.w + bv.w);
            float s1 = v.x + v.y + v.z + v.w;
            float s2 = v.x * v.x + v.y * v.y + v.z * v.z + v.w * v.w;
            s1 = wave_sum(s1);
            s2 = wave_sum(s2);
            const float mu   = s1 * (1.0f / HID);
            const float rstd = rsqrtf(s2 * (1.0f / HID) - mu * mu + 1e-5f);
            float4 o;
            o.x = (v.x - mu) * rstd * gg.x + bb1.x;
            o.y = (v.y - mu) * rstd * gg.y + bb1.y;
            o.z = (v.z - mu) * rstd * gg.z + bb1.z;
            o.w = (v.w - mu) * rstd * gg.w + bb1.w;
            const int grow = row0 + (r ? lr1 : lr0);
            *(float4*)&hdst[(size_t)grow * HID + col] = o;
        }
    }
}

// ---------------------------------------------------------------------------
// Kernel D: GEMM1 (K=256) + GELU + LN2 + GEMM2 (256x4) + select/sigmoid/mask.
// Same 8-rows-per-block layout as kernel C.
// ---------------------------------------------------------------------------
__global__ __launch_bounds__(256) void k_mlp12(
    const float* __restrict__ h1n, const float* __restrict__ h2n,
    const float* __restrict__ W11, const float* __restrict__ b11,
    const float* __restrict__ W21, const float* __restrict__ b21,
    const float* __restrict__ W12, const float* __restrict__ b12,
    const float* __restrict__ W22, const float* __restrict__ b22,
    const float* __restrict__ g2, const float* __restrict__ be2,
    const float* __restrict__ keepf, const float* __restrict__ mask,
    float* __restrict__ dout)
{
    __shared__ float h_lds[8][HID];
    const int tid  = threadIdx.x;
    const int row0 = blockIdx.x * 8;
    const int lane = tid & 63;
    const int rg   = tid >> 6;
    const int col  = lane * 4;
    const int lr0  = rg * 2, lr1 = lr0 + 1;

    const float4 gg  = *(const float4*)&g2[col];
    const float4 bb2 = *(const float4*)&be2[col];

    float res[2][2][4];   // [branch][local row of wave][c]

    #pragma unroll
    for (int br = 0; br < 2; ++br) {
        const float* hsrc = br ? h2n : h1n;
        __syncthreads();
        for (int fi = tid; fi < 8 * 64; fi += 256) {
            const int r = fi >> 6, t = fi & 63;
            *(float4*)&h_lds[r][t * 4] =
                *(const float4*)&hsrc[(size_t)(row0 + r) * HID + t * 4];
        }
        __syncthreads();

        const float* W  = br ? W21 : W11;
        const float* bb = br ? b21 : b11;
        float4 a0 = make_float4(0.f, 0.f, 0.f, 0.f);
        float4 a1 = make_float4(0.f, 0.f, 0.f, 0.f);

        for (int e = 0; e < HID; e += 2) {
            const float2 ya = *(const float2*)&h_lds[lr0][e];
            const float2 yb = *(const float2*)&h_lds[lr1][e];
            const float4 w0 = *(const float4*)&W[(size_t)e * HID + col];
            const float4 w1 = *(const float4*)&W[(size_t)(e + 1) * HID + col];
            a0.x += ya.x * w0.x + ya.y * w1.x;
            a0.y += ya.x * w0.y + ya.y * w1.y;
            a0.z += ya.x * w0.z + ya.y * w1.z;
            a0.w += ya.x * w0.w + ya.y * w1.w;
            a1.x += yb.x * w0.x + yb.y * w1.x;
            a1.y += yb.x * w0.y + yb.y * w1.y;
            a1.z += yb.x * w0.z + yb.y * w1.z;
            a1.w += yb.x * w0.w + yb.y * w1.w;
        }

        const float4 bv = *(const float4*)&bb[col];
        const float* W2 = br ? W22 : W12;
        const float* b2 = br ? b22 : b12;

        #pragma unroll
        for (int r = 0; r < 2; ++r) {
            float4 v = r ? a1 : a0;
            v.x = gelu_exact(v.x + bv.x);
            v.y = gelu_exact(v.y + bv.y);
            v.z = gelu_exact(v.z + bv.z);
            v.w = gelu_exact(v.w + bv.w);
            float s1 = v.x + v.y + v.z + v.w;
            float s2 = v.x * v.x + v.y * v.y + v.z * v.z + v.w * v.w;
            s1 = wave_sum(s1);
            s2 = wave_sum(s2);
            const float mu   = s1 * (1.0f / HID);
            const float rstd = rsqrtf(s2 * (1.0f / HID) - mu * mu + 1e-5f);
            float zn[4];
            zn[0] = (v.x - mu) * rstd * gg.x + bb2.x;
            zn[1] = (v.y - mu) * rstd * gg.y + bb2.y;
            zn[2] = (v.z - mu) * rstd * gg.z + bb2.z;
            zn[3] = (v.w - mu) * rstd * gg.w + bb2.w;

            float p[4] = {0.f, 0.f, 0.f, 0.f};
            #pragma unroll
            for (int k = 0; k < 4; ++k) {
                const float4 w4 = *(const float4*)&W2[(size_t)(col + k) * 4];
                p[0] += zn[k] * w4.x;
                p[1] += zn[k] * w4.y;
                p[2] += zn[k] * w4.z;
                p[3] += zn[k] * w4.w;
            }
            #pragma unroll
            for (int c = 0; c < 4; ++c) {
                p[c] = wave_sum(p[c]);
                res[br][r][c] = p[c] + b2[c];
            }
        }
    }

    if (lane == 0) {
        #pragma unroll
        for (int r = 0; r < 2; ++r) {
            const int grow = row0 + lr0 + r;
            const float kf = keepf[grow];
            const float m  = mask[grow];
            const float* sel = (kf > 0.5f) ? res[0][r] : res[1][r];
            const float x1 = sigmoidf(sel[0]) * m;
            const float y1 = sigmoidf(sel[1]) * m;
            const float w  = sigmoidf(sel[2]) * m;
            const float h  = sigmoidf(sel[3]) * m;
            dout[grow]            = x1;
            dout[NROWS + grow]    = y1;
            dout[2 * NROWS + grow] = x1 + w;
            dout[3 * NROWS + grow] = y1 + h;
        }
    }
}

// ---------------------------------------------------------------------------
extern "C" void kernel_launch(void* const* d_in, const int* in_sizes, int n_in,
                              void* d_out, int out_size, void* d_ws, size_t ws_size,
                              hipStream_t stream)
{
    const float* hm   = (const float*)d_in[0];
    const float* mask = (const float*)d_in[1];
    const float* Wh   = (const float*)d_in[2];
    const float* bh   = (const float*)d_in[3];
    const float* Wk   = (const float*)d_in[4];
    const float* bk   = (const float*)d_in[5];
    const float* W10  = (const float*)d_in[6];
    const float* b10  = (const float*)d_in[7];
    const float* W11  = (const float*)d_in[8];
    const float* b11  = (const float*)d_in[9];
    const float* W12  = (const float*)d_in[10];
    const float* b12  = (const float*)d_in[11];
    const float* W20  = (const float*)d_in[12];
    const float* b20  = (const float*)d_in[13];
    const float* W21  = (const float*)d_in[14];
    const float* b21  = (const float*)d_in[15];
    const float* W22  = (const float*)d_in[16];
    const float* b22  = (const float*)d_in[17];
    const float* g0   = (const float*)d_in[18];
    const float* be0  = (const float*)d_in[19];
    const float* g1   = (const float*)d_in[20];
    const float* be1  = (const float*)d_in[21];
    const float* g2   = (const float*)d_in[22];
    const float* be2  = (const float*)d_in[23];

    float* ws    = (float*)d_ws;
    float* y     = ws;                              // 2048*588
    float* h1n   = y + (size_t)NROWS * ELEN;        // 2048*256
    float* h2n   = h1n + (size_t)NROWS * HID;       // 2048*256
    float* keepf = h2n + (size_t)NROWS * HID;       // 2048
    float* dout  = (float*)d_out;

    k_reduce_ln0<<<NROWS, 256, 0, stream>>>(hm, Wh, bh, Wk, bk, g0, be0,
                                            y, keepf, dout + 4 * NROWS);
    k_mlp0<<<NROWS / 8, 256, 0, stream>>>(y, W10, b10, W20, b20, g1, be1,
                                          h1n, h2n);
    k_mlp12<<<NROWS / 8, 256, 0, stream>>>(h1n, h2n, W11, b11, W21, b21,
                                           W12, b12, W22, b22, g2, be2,
                                           keepf, mask, dout);
}

// Round 2
// 547.671 us; speedup vs baseline: 1.1350x; 1.1350x over previous
//
#include <hip/hip_runtime.h>
#include <hip/hip_bf16.h>
#include <math.h>

#define NLAYER 4
#define BSZ 2
#define NHEADS 16
#define ILEN 1024
#define ELEN 588
#define HID 256
#define NROWS (BSZ * ILEN)        // 2048
#define NCH (NLAYER * NHEADS)     // 64
#define S_H ((size_t)(ILEN) * ELEN)          // 602112  (head stride, floats)
#define S_B ((size_t)NHEADS * S_H)           // 9633792 (batch stride)
#define S_L ((size_t)BSZ * S_B)              // 19267584 (layer stride)

typedef float f32x4 __attribute__((ext_vector_type(4)));

__device__ __forceinline__ float gelu_exact(float x) {
    return 0.5f * x * (1.0f + erff(x * 0.70710678118654752440f));
}
__device__ __forceinline__ float sigmoidf(float x) {
    return 1.0f / (1.0f + expf(-x));
}
__device__ __forceinline__ float wave_sum(float v) {
    #pragma unroll
    for (int m = 1; m < 64; m <<= 1) v += __shfl_xor(v, m);
    return v;
}

// ---------------------------------------------------------------------------
// Kernel A: heatmap channel-reduction + logits + LN0, one block per row.
// 308 MB streamed once -> nontemporal loads, 16-deep load pipeline.
// ---------------------------------------------------------------------------
__global__ __launch_bounds__(256) void k_reduce_ln0(
    const float* __restrict__ hm, const float* __restrict__ Wh,
    const float* __restrict__ bh, const float* __restrict__ Wk,
    const float* __restrict__ bk, const float* __restrict__ g0,
    const float* __restrict__ be0, float* __restrict__ y,
    float* __restrict__ out_logits)
{
    const int row = blockIdx.x;           // b*1024 + i
    const int b = row >> 10;
    const int i = row & 1023;
    const int tid = threadIdx.x;

    __shared__ float s_wh[NCH];
    __shared__ float s_wk[ELEN];
    __shared__ float s_red[12];
    __shared__ float s_bcast[2];

    if (tid < NCH) s_wh[tid] = Wh[tid];
    for (int e = tid; e < ELEN; e += 256) s_wk[e] = Wk[e];
    __syncthreads();

    const int f4 = tid;                   // active for f4 < 147 (147*4 = 588)
    f32x4 acc = {0.f, 0.f, 0.f, 0.f};

    if (f4 < 147) {
        const float* rowbase = hm + (size_t)b * S_B + (size_t)i * ELEN + (size_t)(f4 * 4);
        #pragma unroll 16
        for (int ch = 0; ch < NCH; ++ch) {
            const size_t off = (size_t)(ch >> 4) * S_L + (size_t)(ch & 15) * S_H;
            const f32x4 v = __builtin_nontemporal_load((const f32x4*)(rowbase + off));
            acc += v * s_wh[ch];
        }
        const float bhv = bh[0];
        acc.x += bhv; acc.y += bhv; acc.z += bhv; acc.w += bhv;
    }

    float sx = 0.f, sxx = 0.f, sk = 0.f;
    if (f4 < 147) {
        sx  = acc.x + acc.y + acc.z + acc.w;
        sxx = acc.x * acc.x + acc.y * acc.y + acc.z * acc.z + acc.w * acc.w;
        const float4 wk = *(const float4*)&s_wk[f4 * 4];
        sk  = acc.x * wk.x + acc.y * wk.y + acc.z * wk.z + acc.w * wk.w;
    }
    #pragma unroll
    for (int off = 32; off; off >>= 1) {
        sx  += __shfl_down(sx, off);
        sxx += __shfl_down(sxx, off);
        sk  += __shfl_down(sk, off);
    }
    const int wid = tid >> 6, lane = tid & 63;
    if (lane == 0) { s_red[wid] = sx; s_red[4 + wid] = sxx; s_red[8 + wid] = sk; }
    __syncthreads();
    if (tid == 0) {
        sx  = s_red[0] + s_red[1] + s_red[2] + s_red[3];
        sxx = s_red[4] + s_red[5] + s_red[6] + s_red[7];
        sk  = s_red[8] + s_red[9] + s_red[10] + s_red[11];
        const float mu   = sx * (1.0f / ELEN);
        const float var  = sxx * (1.0f / ELEN) - mu * mu;
        const float rstd = rsqrtf(var + 1e-5f);
        s_bcast[0] = mu; s_bcast[1] = rstd;
        out_logits[row] = sk + bk[0];
    }
    __syncthreads();
    if (f4 < 147) {
        const float mu = s_bcast[0], rstd = s_bcast[1];
        const float4 gv = *(const float4*)&g0[f4 * 4];
        const float4 bv = *(const float4*)&be0[f4 * 4];
        float4 o;
        o.x = (acc.x - mu) * rstd * gv.x + bv.x;
        o.y = (acc.y - mu) * rstd * gv.y + bv.y;
        o.z = (acc.z - mu) * rstd * gv.z + bv.z;
        o.w = (acc.w - mu) * rstd * gv.w + bv.w;
        *(float4*)&y[(size_t)row * ELEN + f4 * 4] = o;
    }
}

// ---------------------------------------------------------------------------
// Kernel B: full MLP, fused. Block = 512 threads (8 waves), 8 rows/block,
// wave = one row (all 256 cols, 4/lane). After the y-stage there are NO
// block barriers: each wave's LN1/GEMM1/LN2/GEMM2 touches only its own row.
// Both branches sequential; select via logits already in d_out.
// ---------------------------------------------------------------------------
__global__ __launch_bounds__(512) void k_mlp_fused(
    const float* __restrict__ y,
    const float* __restrict__ W10, const float* __restrict__ b10,
    const float* __restrict__ W11, const float* __restrict__ b11,
    const float* __restrict__ W12, const float* __restrict__ b12,
    const float* __restrict__ W20, const float* __restrict__ b20,
    const float* __restrict__ W21, const float* __restrict__ b21,
    const float* __restrict__ W22, const float* __restrict__ b22,
    const float* __restrict__ g1, const float* __restrict__ be1,
    const float* __restrict__ g2, const float* __restrict__ be2,
    const float* __restrict__ mask, float* __restrict__ dout)
{
    __shared__ float y_lds[8][ELEN];
    __shared__ float h_lds[8][HID];

    const int tid  = threadIdx.x;
    const int row0 = blockIdx.x * 8;

    for (int fi = tid; fi < 8 * 147; fi += 512) {
        const int r = fi / 147, t = fi % 147;
        *(float4*)&y_lds[r][t * 4] =
            *(const float4*)&y[(size_t)(row0 + r) * ELEN + t * 4];
    }
    __syncthreads();

    const int w    = tid >> 6;      // wave id == local row
    const int lane = tid & 63;
    const int col  = lane * 4;
    const int grow = row0 + w;

    const float4 gg1 = *(const float4*)&g1[col];
    const float4 be1v = *(const float4*)&be1[col];
    const float4 gg2 = *(const float4*)&g2[col];
    const float4 be2v = *(const float4*)&be2[col];

    float res[2][4];

    #pragma unroll
    for (int br = 0; br < 2; ++br) {
        const float* W0  = br ? W20 : W10;
        const float* bb0 = br ? b20 : b10;
        const float* W1  = br ? W21 : W11;
        const float* bb1 = br ? b21 : b11;
        const float* W2  = br ? W22 : W12;
        const float* bb2 = br ? b22 : b12;

        // ---- GEMM0: K = 588 from LDS row, W streamed (L1-shared by 8 waves)
        float4 a = make_float4(0.f, 0.f, 0.f, 0.f);
        for (int e = 0; e < ELEN; e += 4) {
            const float4 ya = *(const float4*)&y_lds[w][e];
            const float4 w0 = *(const float4*)&W0[(size_t)(e + 0) * HID + col];
            const float4 w1 = *(const float4*)&W0[(size_t)(e + 1) * HID + col];
            const float4 w2 = *(const float4*)&W0[(size_t)(e + 2) * HID + col];
            const float4 w3 = *(const float4*)&W0[(size_t)(e + 3) * HID + col];
            a.x += ya.x * w0.x + ya.y * w1.x + ya.z * w2.x + ya.w * w3.x;
            a.y += ya.x * w0.y + ya.y * w1.y + ya.z * w2.y + ya.w * w3.y;
            a.z += ya.x * w0.z + ya.y * w1.z + ya.z * w2.z + ya.w * w3.z;
            a.w += ya.x * w0.w + ya.y * w1.w + ya.z * w2.w + ya.w * w3.w;
        }
        {
            const float4 bv = *(const float4*)&bb0[col];
            a.x = gelu_exact(a.x + bv.x);
            a.y = gelu_exact(a.y + bv.y);
            a.z = gelu_exact(a.z + bv.z);
            a.w = gelu_exact(a.w + bv.w);
        }
        // ---- LN1 (wave-wide; lane holds 4 cols)
        {
            float s1 = wave_sum(a.x + a.y + a.z + a.w);
            float s2 = wave_sum(a.x * a.x + a.y * a.y + a.z * a.z + a.w * a.w);
            const float mu   = s1 * (1.0f / HID);
            const float rstd = rsqrtf(s2 * (1.0f / HID) - mu * mu + 1e-5f);
            float4 o;
            o.x = (a.x - mu) * rstd * gg1.x + be1v.x;
            o.y = (a.y - mu) * rstd * gg1.y + be1v.y;
            o.z = (a.z - mu) * rstd * gg1.z + be1v.z;
            o.w = (a.w - mu) * rstd * gg1.w + be1v.w;
            *(float4*)&h_lds[w][col] = o;   // own row; wave-internal ordering only
        }
        // ---- GEMM1: K = 256 from own LDS row
        float4 c = make_float4(0.f, 0.f, 0.f, 0.f);
        for (int e = 0; e < HID; e += 4) {
            const float4 ha = *(const float4*)&h_lds[w][e];
            const float4 w0 = *(const float4*)&W1[(size_t)(e + 0) * HID + col];
            const float4 w1 = *(const float4*)&W1[(size_t)(e + 1) * HID + col];
            const float4 w2 = *(const float4*)&W1[(size_t)(e + 2) * HID + col];
            const float4 w3 = *(const float4*)&W1[(size_t)(e + 3) * HID + col];
            c.x += ha.x * w0.x + ha.y * w1.x + ha.z * w2.x + ha.w * w3.x;
            c.y += ha.x * w0.y + ha.y * w1.y + ha.z * w2.y + ha.w * w3.y;
            c.z += ha.x * w0.z + ha.y * w1.z + ha.z * w2.z + ha.w * w3.z;
            c.w += ha.x * w0.w + ha.y * w1.w + ha.z * w2.w + ha.w * w3.w;
        }
        {
            const float4 bv = *(const float4*)&bb1[col];
            c.x = gelu_exact(c.x + bv.x);
            c.y = gelu_exact(c.y + bv.y);
            c.z = gelu_exact(c.z + bv.z);
            c.w = gelu_exact(c.w + bv.w);
        }
        // ---- LN2 in registers
        float zn[4];
        {
            float s1 = wave_sum(c.x + c.y + c.z + c.w);
            float s2 = wave_sum(c.x * c.x + c.y * c.y + c.z * c.z + c.w * c.w);
            const float mu   = s1 * (1.0f / HID);
            const float rstd = rsqrtf(s2 * (1.0f / HID) - mu * mu + 1e-5f);
            zn[0] = (c.x - mu) * rstd * gg2.x + be2v.x;
            zn[1] = (c.y - mu) * rstd * gg2.y + be2v.y;
            zn[2] = (c.z - mu) * rstd * gg2.z + be2v.z;
            zn[3] = (c.w - mu) * rstd * gg2.w + be2v.w;
        }
        // ---- GEMM2: 256 x 4 (row dot; wave reduce)
        float p[4] = {0.f, 0.f, 0.f, 0.f};
        #pragma unroll
        for (int k = 0; k < 4; ++k) {
            const float4 w4 = *(const float4*)&W2[(size_t)(col + k) * 4];
            p[0] += zn[k] * w4.x;
            p[1] += zn[k] * w4.y;
            p[2] += zn[k] * w4.z;
            p[3] += zn[k] * w4.w;
        }
        #pragma unroll
        for (int cc = 0; cc < 4; ++cc)
            res[br][cc] = wave_sum(p[cc]) + bb2[cc];
    }

    if (lane == 0) {
        const float logit = dout[4 * NROWS + grow];   // written by kernel A
        const float m = mask[grow];
        const float* sel = (logit > 0.f) ? res[0] : res[1];
        const float x1 = sigmoidf(sel[0]) * m;
        const float y1 = sigmoidf(sel[1]) * m;
        const float ww = sigmoidf(sel[2]) * m;
        const float hh = sigmoidf(sel[3]) * m;
        dout[grow]             = x1;
        dout[NROWS + grow]     = y1;
        dout[2 * NROWS + grow] = x1 + ww;
        dout[3 * NROWS + grow] = y1 + hh;
    }
}

// ---------------------------------------------------------------------------
extern "C" void kernel_launch(void* const* d_in, const int* in_sizes, int n_in,
                              void* d_out, int out_size, void* d_ws, size_t ws_size,
                              hipStream_t stream)
{
    const float* hm   = (const float*)d_in[0];
    const float* mask = (const float*)d_in[1];
    const float* Wh   = (const float*)d_in[2];
    const float* bh   = (const float*)d_in[3];
    const float* Wk   = (const float*)d_in[4];
    const float* bk   = (const float*)d_in[5];
    const float* W10  = (const float*)d_in[6];
    const float* b10  = (const float*)d_in[7];
    const float* W11  = (const float*)d_in[8];
    const float* b11  = (const float*)d_in[9];
    const float* W12  = (const float*)d_in[10];
    const float* b12  = (const float*)d_in[11];
    const float* W20  = (const float*)d_in[12];
    const float* b20  = (const float*)d_in[13];
    const float* W21  = (const float*)d_in[14];
    const float* b21  = (const float*)d_in[15];
    const float* W22  = (const float*)d_in[16];
    const float* b22  = (const float*)d_in[17];
    const float* g0   = (const float*)d_in[18];
    const float* be0  = (const float*)d_in[19];
    const float* g1   = (const float*)d_in[20];
    const float* be1  = (const float*)d_in[21];
    const float* g2   = (const float*)d_in[22];
    const float* be2  = (const float*)d_in[23];

    float* ws   = (float*)d_ws;
    float* y    = ws;                              // 2048*588
    float* dout = (float*)d_out;

    k_reduce_ln0<<<NROWS, 256, 0, stream>>>(hm, Wh, bh, Wk, bk, g0, be0,
                                            y, dout + 4 * NROWS);
    k_mlp_fused<<<NROWS / 8, 512, 0, stream>>>(y, W10, b10, W11, b11, W12, b12,
                                               W20, b20, W21, b21, W22, b22,
                                               g1, be1, g2, be2, mask, dout);
}

// Round 5
// 538.315 us; speedup vs baseline: 1.1547x; 1.0174x over previous
//
#include <hip/hip_runtime.h>
#include <hip/hip_bf16.h>
#include <math.h>

#define NLAYER 4
#define BSZ 2
#define NHEADS 16
#define ILEN 1024
#define ELEN 588
#define HID 256
#define NROWS (BSZ * ILEN)        // 2048
#define NCH (NLAYER * NHEADS)     // 64
#define S_H ((size_t)(ILEN) * ELEN)          // 602112  (head stride, floats)
#define S_B ((size_t)NHEADS * S_H)           // 9633792 (batch stride)
#define S_L ((size_t)BSZ * S_B)              // 19267584 (layer stride)

typedef float f32x4 __attribute__((ext_vector_type(4)));

__device__ __forceinline__ float gelu_exact(float x) {
    return 0.5f * x * (1.0f + erff(x * 0.70710678118654752440f));
}
__device__ __forceinline__ float sigmoidf(float x) {
    return 1.0f / (1.0f + expf(-x));
}
__device__ __forceinline__ float wave_sum(float v) {
    #pragma unroll
    for (int m = 1; m < 64; m <<= 1) v += __shfl_xor(v, m);
    return v;
}

// ---------------------------------------------------------------------------
// Kernel A: heatmap channel-reduction + logits + LN0.
// 4 consecutive rows per block (contiguous in memory -> flat float4 = 4*tid),
// block=640 (588 active = 92%), grid=512 (2 blocks/CU).
// ---------------------------------------------------------------------------
__global__ __launch_bounds__(640) void k_reduce_ln0(
    const float* __restrict__ hm, const float* __restrict__ Wh,
    const float* __restrict__ bh, const float* __restrict__ Wk,
    const float* __restrict__ bk, const float* __restrict__ g0,
    const float* __restrict__ be0, float* __restrict__ y,
    float* __restrict__ out_logits)
{
    const int row0 = blockIdx.x * 4;      // never straddles b (1024 % 4 == 0)
    const int b    = row0 >> 10;
    const int i0   = row0 & 1023;
    const int tid  = threadIdx.x;

    __shared__ float s_wh[NCH];
    __shared__ float s_wk[ELEN];
    __shared__ float p_sx[588], p_sxx[588], p_sk[588];
    __shared__ float s_stat[4][2];

    if (tid < NCH) s_wh[tid] = Wh[tid];
    for (int e = tid; e < ELEN; e += 640) s_wk[e] = Wk[e];
    __syncthreads();

    const int q = tid;                    // flat float4 index in 4-row group
    f32x4 acc = {0.f, 0.f, 0.f, 0.f};
    int r = 0, e4 = 0;

    if (q < 588) {
        r  = q / 147;                     // local row 0..3
        e4 = q - r * 147;                 // float4 index within row
        const f32x4* base = (const f32x4*)(hm + (size_t)b * S_B + (size_t)i0 * ELEN) + q;
        #pragma unroll 8
        for (int ch = 0; ch < NCH; ++ch) {
            const size_t off4 = ((size_t)(ch >> 4) * S_L + (size_t)(ch & 15) * S_H) >> 2;
            const f32x4 v = __builtin_nontemporal_load(base + off4);
            acc += v * s_wh[ch];
        }
        const float bhv = bh[0];
        acc.x += bhv; acc.y += bhv; acc.z += bhv; acc.w += bhv;

        const f32x4 wk = *(const f32x4*)&s_wk[e4 * 4];
        p_sx[q]  = acc.x + acc.y + acc.z + acc.w;
        p_sxx[q] = acc.x * acc.x + acc.y * acc.y + acc.z * acc.z + acc.w * acc.w;
        p_sk[q]  = acc.x * wk.x + acc.y * wk.y + acc.z * wk.z + acc.w * wk.w;
    }
    __syncthreads();

    const int w    = tid >> 6;
    const int lane = tid & 63;
    if (w < 4) {                          // wave w reduces row w (147 partials)
        float rsx = 0.f, rsxx = 0.f, rsk = 0.f;
        for (int j = w * 147 + lane; j < w * 147 + 147; j += 64) {
            rsx  += p_sx[j];
            rsxx += p_sxx[j];
            rsk  += p_sk[j];
        }
        rsx  = wave_sum(rsx);
        rsxx = wave_sum(rsxx);
        rsk  = wave_sum(rsk);
        if (lane == 0) {
            const float mu   = rsx * (1.0f / ELEN);
            const float var  = rsxx * (1.0f / ELEN) - mu * mu;
            s_stat[w][0] = mu;
            s_stat[w][1] = rsqrtf(var + 1e-5f);
            out_logits[row0 + w] = rsk + bk[0];
        }
    }
    __syncthreads();

    if (q < 588) {
        const float mu   = s_stat[r][0];
        const float rstd = s_stat[r][1];
        const f32x4 gv = *(const f32x4*)&g0[e4 * 4];
        const f32x4 bv = *(const f32x4*)&be0[e4 * 4];
        f32x4 o;
        o.x = (acc.x - mu) * rstd * gv.x + bv.x;
        o.y = (acc.y - mu) * rstd * gv.y + bv.y;
        o.z = (acc.z - mu) * rstd * gv.z + bv.z;
        o.w = (acc.w - mu) * rstd * gv.w + bv.w;
        *((f32x4*)(y + (size_t)row0 * ELEN) + q) = o;
    }
}

// ---------------------------------------------------------------------------
// Kernel B: one branch per block. Grid 512 = 256 row-groups x 2 branches,
// block 256 (4 waves), 8 rows/block, 2 rows/wave. W staged in LDS chunks
// (shared by all 4 waves); y/h broadcast-read from LDS.
// ---------------------------------------------------------------------------
__global__ __launch_bounds__(256) void k_mlp_branch(
    const float* __restrict__ y,
    const float* __restrict__ W0a, const float* __restrict__ b0a,
    const float* __restrict__ W1a, const float* __restrict__ b1a,
    const float* __restrict__ W2a, const float* __restrict__ b2a,
    const float* __restrict__ W0b, const float* __restrict__ b0b,
    const float* __restrict__ W1b, const float* __restrict__ b1b,
    const float* __restrict__ W2b, const float* __restrict__ b2b,
    const float* __restrict__ g1, const float* __restrict__ be1,
    const float* __restrict__ g2, const float* __restrict__ be2,
    float* __restrict__ res1, float* __restrict__ res2)
{
    __shared__ float y_lds[8][ELEN];      // 18816 B
    __shared__ float w_lds[42 * HID];     // 43008 B
    __shared__ float h_lds[8][HID];       //  8192 B   -> ~70 KB total

    const int bid  = blockIdx.x;
    const int br   = bid >> 8;            // 0: branch1, 1: branch2
    const int rb   = bid & 255;
    const int row0 = rb * 8;
    const int tid  = threadIdx.x;

    const float* W0 = br ? W0b : W0a;
    const float* b0 = br ? b0b : b0a;
    const float* W1 = br ? W1b : W1a;
    const float* b1 = br ? b1b : b1a;
    const float* W2 = br ? W2b : W2a;
    const float* b2 = br ? b2b : b2a;
    float*      res = br ? res2 : res1;

    // stage y rows (8 x 147 float4)
    for (int fi = tid; fi < 8 * 147; fi += 256) {
        const int r = fi / 147, t = fi - r * 147;
        *(f32x4*)&y_lds[r][t * 4] =
            *((const f32x4*)(y + (size_t)(row0 + r) * ELEN) + t);
    }

    const int w    = tid >> 6;
    const int lane = tid & 63;
    const int col  = lane * 4;
    const int lr0  = 2 * w, lr1 = 2 * w + 1;

    // ---- GEMM0: K = 588, chunks of 42
    f32x4 a0 = {0.f, 0.f, 0.f, 0.f};
    f32x4 a1 = {0.f, 0.f, 0.f, 0.f};
    for (int c = 0; c < 14; ++c) {
        const int k0 = c * 42;
        __syncthreads();
        for (int fi = tid; fi < 42 * 64; fi += 256)
            ((f32x4*)w_lds)[fi] =
                *((const f32x4*)(W0 + (size_t)(k0 + (fi >> 6)) * HID) + (fi & 63));
        __syncthreads();
        #pragma unroll
        for (int e = 0; e < 42; e += 2) {
            const f32x4 w0 = *(const f32x4*)&w_lds[(e + 0) * HID + col];
            const f32x4 w1 = *(const f32x4*)&w_lds[(e + 1) * HID + col];
            const float2 ya = *(const float2*)&y_lds[lr0][k0 + e];
            const float2 yb = *(const float2*)&y_lds[lr1][k0 + e];
            a0 += w0 * ya.x + w1 * ya.y;
            a1 += w0 * yb.x + w1 * yb.y;
        }
    }

    // bias + GELU + LN1 -> h_lds (own rows; wave-internal ordering only)
    {
        const f32x4 bv  = *(const f32x4*)&b0[col];
        const f32x4 gg  = *(const f32x4*)&g1[col];
        const f32x4 bb  = *(const f32x4*)&be1[col];
        #pragma unroll
        for (int rr = 0; rr < 2; ++rr) {
            f32x4 v = rr ? a1 : a0;
            v.x = gelu_exact(v.x + bv.x);
            v.y = gelu_exact(v.y + bv.y);
            v.z = gelu_exact(v.z + bv.z);
            v.w = gelu_exact(v.w + bv.w);
            const float s1 = wave_sum(v.x + v.y + v.z + v.w);
            const float s2 = wave_sum(v.x * v.x + v.y * v.y + v.z * v.z + v.w * v.w);
            const float mu   = s1 * (1.0f / HID);
            const float rstd = rsqrtf(s2 * (1.0f / HID) - mu * mu + 1e-5f);
            f32x4 o;
            o.x = (v.x - mu) * rstd * gg.x + bb.x;
            o.y = (v.y - mu) * rstd * gg.y + bb.y;
            o.z = (v.z - mu) * rstd * gg.z + bb.z;
            o.w = (v.w - mu) * rstd * gg.w + bb.w;
            *(f32x4*)&h_lds[rr ? lr1 : lr0][col] = o;
        }
    }

    // ---- GEMM1: K = 256, chunks of 32
    f32x4 c0 = {0.f, 0.f, 0.f, 0.f};
    f32x4 c1 = {0.f, 0.f, 0.f, 0.f};
    for (int c = 0; c < 8; ++c) {
        const int k0 = c * 32;
        __syncthreads();
        for (int fi = tid; fi < 32 * 64; fi += 256)
            ((f32x4*)w_lds)[fi] =
                *((const f32x4*)(W1 + (size_t)(k0 + (fi >> 6)) * HID) + (fi & 63));
        __syncthreads();
        #pragma unroll
        for (int e = 0; e < 32; e += 2) {
            const f32x4 w0 = *(const f32x4*)&w_lds[(e + 0) * HID + col];
            const f32x4 w1 = *(const f32x4*)&w_lds[(e + 1) * HID + col];
            const float2 ha = *(const float2*)&h_lds[lr0][k0 + e];
            const float2 hb = *(const float2*)&h_lds[lr1][k0 + e];
            c0 += w0 * ha.x + w1 * ha.y;
            c1 += w0 * hb.x + w1 * hb.y;
        }
    }

    // bias + GELU + LN2 + GEMM2 (256 -> 4) + wave reduce
    {
        const f32x4 bv = *(const f32x4*)&b1[col];
        const f32x4 gg = *(const f32x4*)&g2[col];
        const f32x4 bb = *(const f32x4*)&be2[col];
        #pragma unroll
        for (int rr = 0; rr < 2; ++rr) {
            f32x4 v = rr ? c1 : c0;
            v.x = gelu_exact(v.x + bv.x);
            v.y = gelu_exact(v.y + bv.y);
            v.z = gelu_exact(v.z + bv.z);
            v.w = gelu_exact(v.w + bv.w);
            const float s1 = wave_sum(v.x + v.y + v.z + v.w);
            const float s2 = wave_sum(v.x * v.x + v.y * v.y + v.z * v.z + v.w * v.w);
            const float mu   = s1 * (1.0f / HID);
            const float rstd = rsqrtf(s2 * (1.0f / HID) - mu * mu + 1e-5f);
            float zn[4];
            zn[0] = (v.x - mu) * rstd * gg.x + bb.x;
            zn[1] = (v.y - mu) * rstd * gg.y + bb.y;
            zn[2] = (v.z - mu) * rstd * gg.z + bb.z;
            zn[3] = (v.w - mu) * rstd * gg.w + bb.w;

            float p[4] = {0.f, 0.f, 0.f, 0.f};
            #pragma unroll
            for (int k = 0; k < 4; ++k) {
                const f32x4 w4 = *(const f32x4*)&W2[(size_t)(col + k) * 4];
                p[0] += zn[k] * w4.x;
                p[1] += zn[k] * w4.y;
                p[2] += zn[k] * w4.z;
                p[3] += zn[k] * w4.w;
            }
            f32x4 out;
            out.x = wave_sum(p[0]) + b2[0];
            out.y = wave_sum(p[1]) + b2[1];
            out.z = wave_sum(p[2]) + b2[2];
            out.w = wave_sum(p[3]) + b2[3];
            if (lane == 0)
                *(f32x4*)&res[(size_t)(row0 + (rr ? lr1 : lr0)) * 4] = out;
        }
    }
}

// ---------------------------------------------------------------------------
// Kernel C: select + sigmoid + mask + final layout. 2048 threads.
// ---------------------------------------------------------------------------
__global__ __launch_bounds__(256) void k_select(
    const float* __restrict__ res1, const float* __restrict__ res2,
    const float* __restrict__ mask, float* __restrict__ dout)
{
    const int row = blockIdx.x * 256 + threadIdx.x;
    if (row >= NROWS) return;
    const float logit = dout[4 * NROWS + row];
    const float m = mask[row];
    const f32x4 s = (logit > 0.f) ? *(const f32x4*)&res1[(size_t)row * 4]
                                  : *(const f32x4*)&res2[(size_t)row * 4];
    const float x1 = sigmoidf(s.x) * m;
    const float y1 = sigmoidf(s.y) * m;
    const float ww = sigmoidf(s.z) * m;
    const float hh = sigmoidf(s.w) * m;
    dout[row]             = x1;
    dout[NROWS + row]     = y1;
    dout[2 * NROWS + row] = x1 + ww;
    dout[3 * NROWS + row] = y1 + hh;
}

// ---------------------------------------------------------------------------
extern "C" void kernel_launch(void* const* d_in, const int* in_sizes, int n_in,
                              void* d_out, int out_size, void* d_ws, size_t ws_size,
                              hipStream_t stream)
{
    const float* hm   = (const float*)d_in[0];
    const float* mask = (const float*)d_in[1];
    const float* Wh   = (const float*)d_in[2];
    const float* bh   = (const float*)d_in[3];
    const float* Wk   = (const float*)d_in[4];
    const float* bk   = (const float*)d_in[5];
    const float* W10  = (const float*)d_in[6];
    const float* b10  = (const float*)d_in[7];
    const float* W11  = (const float*)d_in[8];
    const float* b11  = (const float*)d_in[9];
    const float* W12  = (const float*)d_in[10];
    const float* b12  = (const float*)d_in[11];
    const float* W20  = (const float*)d_in[12];
    const float* b20  = (const float*)d_in[13];
    const float* W21  = (const float*)d_in[14];
    const float* b21  = (const float*)d_in[15];
    const float* W22  = (const float*)d_in[16];
    const float* b22  = (const float*)d_in[17];
    const float* g0   = (const float*)d_in[18];
    const float* be0  = (const float*)d_in[19];
    const float* g1   = (const float*)d_in[20];
    const float* be1  = (const float*)d_in[21];
    const float* g2   = (const float*)d_in[22];
    const float* be2  = (const float*)d_in[23];

    float* ws   = (float*)d_ws;
    float* y    = ws;                                   // 2048*588
    float* res1 = y + (size_t)NROWS * ELEN;             // 2048*4
    float* res2 = res1 + (size_t)NROWS * 4;             // 2048*4
    float* dout = (float*)d_out;

    k_reduce_ln0<<<NROWS / 4, 640, 0, stream>>>(hm, Wh, bh, Wk, bk, g0, be0,
                                                y, dout + 4 * NROWS);
    k_mlp_branch<<<512, 256, 0, stream>>>(y,
                                          W10, b10, W11, b11, W12, b12,
                                          W20, b20, W21, b21, W22, b22,
                                          g1, be1, g2, be2, res1, res2);
    k_select<<<NROWS / 256, 256, 0, stream>>>(res1, res2, mask, dout);
}